// Round 1
// baseline (990.139 us; speedup 1.0000x reference)
//
#include <hip/hip_runtime.h>
#include <hip/hip_bf16.h>
#include <math.h>

#define LNUM 2
#define BB 16
#define SS 256
#define DD 512
#define HH 8
#define DHH 64
#define MM (BB*SS)     // 4096 tokens
#define KDIM 512
#define NDIM 512

typedef __attribute__((ext_vector_type(8))) short bf16x8;
typedef __attribute__((ext_vector_type(4))) float f32x4;

__device__ __forceinline__ unsigned short f2bf(float f) {
  union { float f; unsigned u; } c; c.f = f;
  unsigned u = c.u;
  return (unsigned short)((u + 0x7fffu + ((u >> 16) & 1u)) >> 16);
}

// ---- weight prep: transpose + cast to bf16 -------------------------------
// src (L,D,D) row-major [l][k][n] -> dst bf16 [l][n][k]
__global__ __launch_bounds__(256) void tc_reg(const float* __restrict__ src,
                                              unsigned short* __restrict__ dst) {
  int idx = blockIdx.x * 256 + threadIdx.x;      // 0 .. L*D*D-1
  int l = idx >> 18;
  int r = idx & 262143;
  int n = r >> 9;
  int k = r & 511;
  dst[idx] = f2bf(src[(size_t)l * 262144 + (size_t)k * 512 + n]);
}

// src (L,H,D,DH) [l][h][d][e] -> dst bf16 [l][n=h*64+e][k=d]
__global__ __launch_bounds__(256) void tc_qkv(const float* __restrict__ src,
                                              unsigned short* __restrict__ dst) {
  int idx = blockIdx.x * 256 + threadIdx.x;
  int l = idx >> 18;
  int r = idx & 262143;
  int n = r >> 9;
  int k = r & 511;
  int h = n >> 6;
  int e = n & 63;
  dst[idx] = f2bf(src[(size_t)l * 262144 + (size_t)h * 32768 + (size_t)k * 64 + e]);
}

// ---- positional embedding add --------------------------------------------
__global__ __launch_bounds__(256) void posadd(const float* __restrict__ x,
                                              const float* __restrict__ pe,
                                              float* __restrict__ h) {
  int idx = blockIdx.x * 256 + threadIdx.x;      // float4 index, total 524288
  float4 xv = reinterpret_cast<const float4*>(x)[idx];
  float4 pv = reinterpret_cast<const float4*>(pe)[idx & 32767];
  xv.x += pv.x; xv.y += pv.y; xv.z += pv.z; xv.w += pv.w;
  reinterpret_cast<float4*>(h)[idx] = xv;
}

// ---- bf16 MFMA GEMM:  Y[M x 512] = act(X[M x 512] @ W + bias) ------------
// WT is pre-transposed bf16 [n][k]. ACT: 0 none, 1 elu+1, 2 gelu(tanh)
template<int ACT>
__global__ __launch_bounds__(256) void gemm_k(const float* __restrict__ X,
                                              const unsigned short* __restrict__ WT,
                                              const float* __restrict__ bias,
                                              float* __restrict__ Y) {
  __shared__ unsigned short As[128 * 40];   // pad to 40 shorts/row (80B, 16B-aligned)
  __shared__ unsigned short Bs[128 * 40];
  const int t = threadIdx.x;
  const int m0 = blockIdx.x * 128;
  const int n0 = blockIdx.y * 128;
  const int lane = t & 63;
  const int w = t >> 6;
  const int wrow = (w >> 1) * 64;
  const int wcol = (w & 1) * 64;
  const int frow = lane & 15;
  const int kg = lane >> 4;
  const int rowS = t >> 3;     // 0..31
  const int quad = t & 7;      // 0..7
  f32x4 acc[4][4] = {};

  for (int kt = 0; kt < KDIM; kt += 32) {
#pragma unroll
    for (int r4 = 0; r4 < 4; ++r4) {
      int row = rowS + r4 * 32;
      float4 f = *reinterpret_cast<const float4*>(&X[(size_t)(m0 + row) * KDIM + kt + quad * 4]);
      ushort4 b4;
      b4.x = f2bf(f.x); b4.y = f2bf(f.y); b4.z = f2bf(f.z); b4.w = f2bf(f.w);
      *reinterpret_cast<ushort4*>(&As[row * 40 + quad * 4]) = b4;
      ushort4 wv = *reinterpret_cast<const ushort4*>(&WT[(size_t)(n0 + row) * KDIM + kt + quad * 4]);
      *reinterpret_cast<ushort4*>(&Bs[row * 40 + quad * 4]) = wv;
    }
    __syncthreads();
    bf16x8 av[4], bv[4];
#pragma unroll
    for (int i = 0; i < 4; ++i) {
      av[i] = *reinterpret_cast<const bf16x8*>(&As[(wrow + i * 16 + frow) * 40 + kg * 8]);
      bv[i] = *reinterpret_cast<const bf16x8*>(&Bs[(wcol + i * 16 + frow) * 40 + kg * 8]);
    }
#pragma unroll
    for (int mi = 0; mi < 4; ++mi)
#pragma unroll
      for (int ni = 0; ni < 4; ++ni)
        acc[mi][ni] = __builtin_amdgcn_mfma_f32_16x16x32_bf16(av[mi], bv[ni], acc[mi][ni], 0, 0, 0);
    __syncthreads();
  }

#pragma unroll
  for (int mi = 0; mi < 4; ++mi) {
#pragma unroll
    for (int ni = 0; ni < 4; ++ni) {
      int col = n0 + wcol + ni * 16 + frow;
      float bcol = bias[col];
#pragma unroll
      for (int j = 0; j < 4; ++j) {
        int row = m0 + wrow + mi * 16 + kg * 4 + j;
        float v = acc[mi][ni][j] + bcol;
        if (ACT == 1) v = (v > 0.f) ? (v + 1.f) : expf(v);
        else if (ACT == 2) {
          float u = 0.7978845608028654f * (v + 0.044715f * v * v * v);
          v = 0.5f * v * (1.f + tanhf(u));
        }
        Y[(size_t)row * NDIM + col] = v;
      }
    }
  }
}

// ---- linear attention (per b,h block) ------------------------------------
__global__ __launch_bounds__(256) void attn_k(const float* __restrict__ Q,
                                              const float* __restrict__ K,
                                              const float* __restrict__ V,
                                              float* __restrict__ att) {
  int bh = blockIdx.x;              // b*8 + h
  int b = bh >> 3, h = bh & 7;
  size_t base = (size_t)b * SS * DD + (size_t)h * 64;
  int t = threadIdx.x;
  int e = t & 63;
  int si = t >> 6;                  // 4 seq slices
  float kv = 0.f, ks = 0.f;
  for (int s = si * 64; s < si * 64 + 64; ++s) {
    float kx = K[base + (size_t)s * DD + e];
    float vx = V[base + (size_t)s * DD + e];
    kv = fmaf(kx, vx, kv);
    ks += kx;
  }
  __shared__ float skv[4][64], sks[4][64];
  skv[si][e] = kv; sks[si][e] = ks;
  __syncthreads();
  float kvT = skv[0][e] + skv[1][e] + skv[2][e] + skv[3][e];
  float ksT = sks[0][e] + sks[1][e] + sks[2][e] + sks[3][e];
  for (int s = si * 64; s < si * 64 + 64; ++s) {
    float q = Q[base + (size_t)s * DD + e];
    att[base + (size_t)s * DD + e] = q * kvT / fmaf(q, ksT, 1e-6f);
  }
}

// ---- layernorm of (a + res) ----------------------------------------------
__global__ __launch_bounds__(256) void ln_k(const float* __restrict__ a,
                                            const float* __restrict__ r,
                                            const float* __restrict__ sc,
                                            const float* __restrict__ bi,
                                            float* __restrict__ out) {
  int row = blockIdx.x;
  int t = threadIdx.x;
  size_t base = (size_t)row * 512;
  float x0 = a[base + t] + r[base + t];
  float x1 = a[base + 256 + t] + r[base + 256 + t];
  float s1 = x0 + x1;
  float s2 = x0 * x0 + x1 * x1;
  for (int off = 32; off; off >>= 1) {
    s1 += __shfl_down(s1, off);
    s2 += __shfl_down(s2, off);
  }
  __shared__ float w1[4], w2[4];
  int lane = t & 63, w = t >> 6;
  if (lane == 0) { w1[w] = s1; w2[w] = s2; }
  __syncthreads();
  float S1 = w1[0] + w1[1] + w1[2] + w1[3];
  float S2 = w2[0] + w2[1] + w2[2] + w2[3];
  float mean = S1 * (1.f / 512.f);
  float var = S2 * (1.f / 512.f) - mean * mean;
  float rstd = rsqrtf(var + 1e-6f);
  out[base + t]       = (x0 - mean) * rstd * sc[t] + bi[t];
  out[base + 256 + t] = (x1 - mean) * rstd * sc[256 + t] + bi[256 + t];
}

// ---- final projection: partial sums over K chunks ------------------------
// hf [16][131072]; W [131072][512]; 256 chunks x 512 rows; grid.y selects Wm/Wlv
__global__ __launch_bounds__(256) void proj_k(const float* __restrict__ hf,
                                              const float* __restrict__ Wm,
                                              const float* __restrict__ Wlv,
                                              float* __restrict__ partial) {
  int chunk = blockIdx.x;      // 0..255
  int g = blockIdx.y;          // 0..1
  const float* __restrict__ W = g ? Wlv : Wm;
  __shared__ float sh[16][512];
  int t = threadIdx.x;
  int k0 = chunk * 512;
#pragma unroll
  for (int m = 0; m < 16; ++m) {
    sh[m][t]       = hf[(size_t)m * 131072 + k0 + t];
    sh[m][256 + t] = hf[(size_t)m * 131072 + k0 + 256 + t];
  }
  __syncthreads();
  float acc0[16] = {}, acc1[16] = {};
  for (int kk = 0; kk < 512; kk += 4) {
    float4 sv[16];
#pragma unroll
    for (int m = 0; m < 16; ++m) sv[m] = *reinterpret_cast<const float4*>(&sh[m][kk]);
#pragma unroll
    for (int u = 0; u < 4; ++u) {
      const float* wr = W + (size_t)(k0 + kk + u) * 512;
      float w0 = wr[t];
      float w1 = wr[256 + t];
#pragma unroll
      for (int m = 0; m < 16; ++m) {
        acc0[m] = fmaf(sv[m][u], w0, acc0[m]);
        acc1[m] = fmaf(sv[m][u], w1, acc1[m]);
      }
    }
  }
  float* p = partial + ((size_t)g * 256 + chunk) * 8192;
#pragma unroll
  for (int m = 0; m < 16; ++m) {
    p[m * 512 + t]       = acc0[m];
    p[m * 512 + 256 + t] = acc1[m];
  }
}

__global__ __launch_bounds__(256) void reduce_k(const float* __restrict__ partial,
                                                const float* __restrict__ bm,
                                                const float* __restrict__ blv,
                                                float* __restrict__ out) {
  int idx = blockIdx.x * 256 + threadIdx.x;   // 0..16383
  int g = idx >> 13;
  int mn = idx & 8191;
  const float* p = partial + (size_t)g * 256 * 8192 + mn;
  float s = 0.f;
  for (int c = 0; c < 256; ++c) s += p[(size_t)c * 8192];
  int n = mn & 511;
  s += g ? blv[n] : bm[n];
  out[idx] = s;
}

// ---- host launcher -------------------------------------------------------
extern "C" void kernel_launch(void* const* d_in, const int* in_sizes, int n_in,
                              void* d_out, int out_size, void* d_ws, size_t ws_size,
                              hipStream_t stream) {
  const float* x    = (const float*)d_in[0];
  const float* pe   = (const float*)d_in[1];
  const float* W_in = (const float*)d_in[2];
  const float* b_in = (const float*)d_in[3];
  const float* Wq   = (const float*)d_in[4];
  const float* bq   = (const float*)d_in[5];
  const float* Wk   = (const float*)d_in[6];
  const float* bk   = (const float*)d_in[7];
  const float* Wv   = (const float*)d_in[8];
  const float* bv   = (const float*)d_in[9];
  const float* Wo   = (const float*)d_in[10];
  const float* bo   = (const float*)d_in[11];
  const float* ln1s = (const float*)d_in[12];
  const float* ln1b = (const float*)d_in[13];
  const float* W1   = (const float*)d_in[14];
  const float* b1   = (const float*)d_in[15];
  const float* W2   = (const float*)d_in[16];
  const float* b2   = (const float*)d_in[17];
  const float* ln2s = (const float*)d_in[18];
  const float* ln2b = (const float*)d_in[19];
  const float* Wm   = (const float*)d_in[20];
  const float* bm   = (const float*)d_in[21];
  const float* Wlv  = (const float*)d_in[22];
  const float* blv  = (const float*)d_in[23];
  float* out = (float*)d_out;

  // workspace layout
  char* ws = (char*)d_ws;
  const size_t WSZ = (size_t)LNUM * 512 * 512 * sizeof(unsigned short);  // 1 MiB
  unsigned short* wt_in = (unsigned short*)ws; ws += WSZ;
  unsigned short* wt_q  = (unsigned short*)ws; ws += WSZ;
  unsigned short* wt_k  = (unsigned short*)ws; ws += WSZ;
  unsigned short* wt_v  = (unsigned short*)ws; ws += WSZ;
  unsigned short* wt_o  = (unsigned short*)ws; ws += WSZ;
  unsigned short* wt_1  = (unsigned short*)ws; ws += WSZ;
  unsigned short* wt_2  = (unsigned short*)ws; ws += WSZ;
  const size_t ASZ = (size_t)MM * 512 * sizeof(float);                   // 8 MiB
  float* bh   = (float*)ws; ws += ASZ;
  float* bres = (float*)ws; ws += ASZ;
  float* bq_  = (float*)ws; ws += ASZ;
  float* bk_  = (float*)ws; ws += ASZ;
  float* bv_  = (float*)ws; ws += ASZ;
  float* batt = (float*)ws; ws += ASZ;
  float* bpart = (float*)ws; ws += (size_t)2 * 256 * 8192 * sizeof(float);

  // weight prep (idempotent, every launch)
  tc_reg<<<2048, 256, 0, stream>>>(W_in, wt_in);
  tc_qkv<<<2048, 256, 0, stream>>>(Wq, wt_q);
  tc_qkv<<<2048, 256, 0, stream>>>(Wk, wt_k);
  tc_qkv<<<2048, 256, 0, stream>>>(Wv, wt_v);
  tc_reg<<<2048, 256, 0, stream>>>(Wo, wt_o);
  tc_reg<<<2048, 256, 0, stream>>>(W1, wt_1);
  tc_reg<<<2048, 256, 0, stream>>>(W2, wt_2);

  posadd<<<2048, 256, 0, stream>>>(x, pe, bh);

  dim3 ggrid(32, 4);
  for (int l = 0; l < LNUM; ++l) {
    const unsigned short* win = wt_in + (size_t)l * 262144;
    const unsigned short* wq  = wt_q  + (size_t)l * 262144;
    const unsigned short* wk  = wt_k  + (size_t)l * 262144;
    const unsigned short* wv  = wt_v  + (size_t)l * 262144;
    const unsigned short* wo  = wt_o  + (size_t)l * 262144;
    const unsigned short* w1  = wt_1  + (size_t)l * 262144;
    const unsigned short* w2  = wt_2  + (size_t)l * 262144;

    gemm_k<0><<<ggrid, 256, 0, stream>>>(bh,   win, b_in + l * 512, bres);  // h1 (also residual)
    gemm_k<1><<<ggrid, 256, 0, stream>>>(bres, wq,  bq  + l * 512, bq_);    // Q = elu+1
    gemm_k<1><<<ggrid, 256, 0, stream>>>(bres, wk,  bk  + l * 512, bk_);    // K = elu+1
    gemm_k<0><<<ggrid, 256, 0, stream>>>(bres, wv,  bv  + l * 512, bv_);    // V
    attn_k<<<128, 256, 0, stream>>>(bq_, bk_, bv_, batt);
    gemm_k<2><<<ggrid, 256, 0, stream>>>(batt, wo,  bo  + l * 512, bq_);    // h2 = gelu(att@Wo)
    ln_k<<<4096, 256, 0, stream>>>(bq_, bres, ln1s + l * 512, ln1b + l * 512, bk_);  // x2
    gemm_k<2><<<ggrid, 256, 0, stream>>>(bk_,  w1,  b1  + l * 512, bv_);    // f1
    gemm_k<2><<<ggrid, 256, 0, stream>>>(bv_,  w2,  b2  + l * 512, batt);   // f2
    ln_k<<<4096, 256, 0, stream>>>(batt, bk_, ln2s + l * 512, ln2b + l * 512, bh);   // h
  }

  proj_k<<<dim3(256, 2), 256, 0, stream>>>(bh, Wm, Wlv, bpart);
  reduce_k<<<64, 256, 0, stream>>>(bpart, bm, blv, out);
}